// Round 7
// baseline (29.660 us; speedup 1.0000x reference)
//
#include <hip/hip_runtime.h>
#include <hip/hip_bf16.h>

// StreamingConv == GEMM: C[b,o] = sum_k A[b,k]*W[o,k]; A[256][16384], W[1024][16384] f32.
// R7 = R6 + pipeline depth 2->3 (single variable). R6 analysis: one-deep prefetch
// gives ~6-12 outstanding gl_lds/wave (~3 MB chip-wide = exactly the HBM BDP) and
// vmcnt(6) waits on loads issued only ~600cy earlier (< ~900cy HBM latency).
// Triple-buffer f32 LDS (3 x 48 KB = 144 KB), STAGE(t+2), steady-state vmcnt(12):
// waits span two compute phases (~1200cy) and in-flight bytes triple.
// Kept from R6: XCD co-scheduling (wgid%8 == kb%8 -> A L2-dedup), SKB=32, BN=128,
// global_load_lds f32 XOR-swizzled, bf16 partial slices + permuted epilogue, reduce.

#define CO    1024
#define KTOT  16384
#define BM    256
#define BN    128
#define NB    8                    // n-blocks
#define SKB   32                   // split-K blocks
#define KC    (KTOT / SKB)         // 512
#define BK    32                   // f32 k-step in LDS; row = 128 B = 8 x 16B groups
#define KITERS (KC / BK)           // 16
#define SLICE_ELEMS (BM * CO)      // 262144 bf16 per slice

typedef __attribute__((ext_vector_type(8))) short short8;
typedef __attribute__((ext_vector_type(4))) float f32x4;
typedef __attribute__((ext_vector_type(4))) unsigned short u16x4;

__device__ __forceinline__ unsigned short f2bf(float f) {
    union { __bf16 h; unsigned short u; } c; c.h = (__bf16)f; return c.u;
}

__device__ __forceinline__ void gl_lds16(const float* g, const float* lds_uniform) {
    __builtin_amdgcn_global_load_lds(
        (const __attribute__((address_space(1))) void*)g,
        (__attribute__((address_space(3))) void*)lds_uniform, 16, 0, 0);
}

template <bool USE_WS>
__global__ __launch_bounds__(512, 2)
void sconv_gemm_v7(const float* __restrict__ A, const float* __restrict__ W,
                   float* __restrict__ out, unsigned short* __restrict__ wsb) {
    // f32 tiles, XOR-swizzled: physical 16B-group = logical_group ^ (row & 7)
    __shared__ float lA[3][BM * BK];    // 3 x 32 KB
    __shared__ float lB[3][BN * BK];    // 3 x 16 KB

    const int tid  = threadIdx.x;
    const int wid  = tid >> 6;
    const int lane = tid & 63;

    // decode (kb, nb) from wgid so wgid % 8 == kb % 8 (same-A blocks -> same XCD)
    const int wgid = blockIdx.x;
    const int c  = wgid & 7;
    const int rs = wgid >> 3;
    const int nb = rs & 7;
    const int kb = (rs >> 3) * 8 + c;     // 0..31
    const int bn = nb * BN;
    const int k0 = kb * KC;

    // ---- staging decomposition ----
    // A tile: 256 rows x 8 groups = 2048 16B-slots, 4/thread; B: 128x8 = 1024, 2/thread.
    // slot s -> row = s>>3, phys group = s&7, source k-group = (s&7) ^ (row&7)
    const float* Asrc = A + k0;
    const float* Wsrc = W + (size_t)bn * KTOT + k0;

    int aRow[4], aGk[4], aLds[4];
    #pragma unroll
    for (int j = 0; j < 4; ++j) {
        int s = j * 512 + tid;
        aRow[j] = s >> 3;
        aGk[j]  = (s & 7) ^ (aRow[j] & 7);
        aLds[j] = (j * 512 + wid * 64) * 4;       // wave-uniform base (floats)
    }
    int bRow[2], bGk[2], bLds[2];
    #pragma unroll
    for (int j = 0; j < 2; ++j) {
        int s = j * 512 + tid;
        bRow[j] = s >> 3;
        bGk[j]  = (s & 7) ^ (bRow[j] & 7);
        bLds[j] = (j * 512 + wid * 64) * 4;
    }

#define STAGE(BUF, T) {                                                          \
        _Pragma("unroll")                                                        \
        for (int j = 0; j < 4; ++j)                                              \
            gl_lds16(Asrc + (size_t)aRow[j] * KTOT + (T) * BK + aGk[j] * 4,      \
                     &lA[BUF][aLds[j]]);                                         \
        _Pragma("unroll")                                                        \
        for (int j = 0; j < 2; ++j)                                              \
            gl_lds16(Wsrc + (size_t)bRow[j] * KTOT + (T) * BK + bGk[j] * 4,      \
                     &lB[BUF][bLds[j]]);                                         \
    }
    // 6 gl_lds per thread per STAGE. Steady state: after STAGE(t+2) a wave has
    // 18 outstanding; vmcnt(12) -> tile t's 6 landed (issued 2 iters ago).

    // ---- wave -> 64M x 64N sub-tile (4x2 wave grid over 256x128) ----
    const int wm = (wid >> 1) * 64;
    const int wn = (wid & 1) * 64;
    const int q  = lane >> 4;            // k-quarter: lane k-start = q*8
    const int fr = lane & 15;

    f32x4 acc[4][4] = {};

#define COMPUTE(BUF) {                                                           \
        short8 bf[4];                                                            \
        _Pragma("unroll")                                                        \
        for (int ni = 0; ni < 4; ++ni) {                                         \
            int r = wn + ni * 16 + fr;                                           \
            int sw = r & 7;                                                      \
            f32x4 v0 = *(const f32x4*)&lB[BUF][r * BK + (((q*2)     ^ sw) * 4)]; \
            f32x4 v1 = *(const f32x4*)&lB[BUF][r * BK + (((q*2 + 1) ^ sw) * 4)]; \
            short8 tb;                                                           \
            tb[0]=f2bf(v0[0]); tb[1]=f2bf(v0[1]); tb[2]=f2bf(v0[2]); tb[3]=f2bf(v0[3]); \
            tb[4]=f2bf(v1[0]); tb[5]=f2bf(v1[1]); tb[6]=f2bf(v1[2]); tb[7]=f2bf(v1[3]); \
            bf[ni] = tb;                                                         \
        }                                                                        \
        _Pragma("unroll")                                                        \
        for (int mi = 0; mi < 4; ++mi) {                                         \
            int r = wm + mi * 16 + fr;                                           \
            int sw = r & 7;                                                      \
            f32x4 v0 = *(const f32x4*)&lA[BUF][r * BK + (((q*2)     ^ sw) * 4)]; \
            f32x4 v1 = *(const f32x4*)&lA[BUF][r * BK + (((q*2 + 1) ^ sw) * 4)]; \
            short8 af;                                                           \
            af[0]=f2bf(v0[0]); af[1]=f2bf(v0[1]); af[2]=f2bf(v0[2]); af[3]=f2bf(v0[3]); \
            af[4]=f2bf(v1[0]); af[5]=f2bf(v1[1]); af[6]=f2bf(v1[2]); af[7]=f2bf(v1[3]); \
            _Pragma("unroll")                                                    \
            for (int ni = 0; ni < 4; ++ni)                                       \
                acc[mi][ni] = __builtin_amdgcn_mfma_f32_16x16x32_bf16(           \
                    af, bf[ni], acc[mi][ni], 0, 0, 0);                           \
        }                                                                        \
    }

    // prologue: two tiles in flight
    STAGE(0, 0);
    STAGE(1, 1);
    #pragma unroll
    for (int t = 0; t < KITERS; ++t) {
        const int buf = t % 3;
        const int nb3 = (t + 2) % 3;     // == (t-1)%3: buffer read at iter t-1
        asm volatile("" ::: "memory");
        __builtin_amdgcn_s_barrier();    // all waves done READING buf nb3 (iter t-1)
        asm volatile("" ::: "memory");
        if (t + 2 < KITERS) {
            STAGE(nb3, t + 2);
            asm volatile("s_waitcnt vmcnt(12)" ::: "memory");  // tile t landed
        } else if (t + 1 < KITERS) {
            asm volatile("s_waitcnt vmcnt(6)" ::: "memory");   // tile t landed
        } else {
            asm volatile("s_waitcnt vmcnt(0)" ::: "memory");
        }
        __builtin_amdgcn_s_barrier();    // all waves passed their vmcnt -> buf ready
        asm volatile("" ::: "memory");
        COMPUTE(buf);
    }
#undef STAGE
#undef COMPUTE

    // ---- epilogue. C/D 16x16x32: col = lane&15 (=fr), row = q*4 + j.
    if (USE_WS) {
        // permuted columns within each 64-col wave region: colp = fr*4 + ni
        // (true col = ni*16 + fr); reduce kernel inverts.
        unsigned short* slice = wsb + (size_t)kb * SLICE_ELEMS;
        const int pbase = bn + wn + fr * 4;
        #pragma unroll
        for (int mi = 0; mi < 4; ++mi) {
            #pragma unroll
            for (int j = 0; j < 4; ++j) {
                const int r = wm + mi * 16 + q * 4 + j;
                u16x4 v;
                #pragma unroll
                for (int ni = 0; ni < 4; ++ni) v[ni] = f2bf(acc[mi][ni][j]);
                *(u16x4*)&slice[(size_t)r * CO + pbase] = v;
            }
        }
    } else {
        #pragma unroll
        for (int mi = 0; mi < 4; ++mi)
            #pragma unroll
            for (int ni = 0; ni < 4; ++ni) {
                const int col = bn + wn + ni * 16 + fr;
                #pragma unroll
                for (int j = 0; j < 4; ++j) {
                    const int r = wm + mi * 16 + q * 4 + j;
                    unsafeAtomicAdd(out + (size_t)r * CO + col, acc[mi][ni][j]);
                }
            }
    }
}

// sum 32 bf16 slices elementwise and invert the column permutation.
// group g (u16x4 unit): r = g>>8, p = g&255, c64 = p>>4, L = p&15;
// element e -> out col = c64*64 + e*16 + L.
__global__ __launch_bounds__(256)
void reduce_splitk_v7(const unsigned short* __restrict__ ws, float* __restrict__ out) {
    const int g = blockIdx.x * 256 + threadIdx.x;    // 0 .. 65535
    const u16x4* base = (const u16x4*)ws;
    float s[4] = {0, 0, 0, 0};
    #pragma unroll 8
    for (int sdx = 0; sdx < SKB; ++sdx) {
        u16x4 v = base[(size_t)sdx * (SLICE_ELEMS / 4) + g];
        #pragma unroll
        for (int e = 0; e < 4; ++e) {
            unsigned int u = ((unsigned int)v[e]) << 16;
            s[e] += __builtin_bit_cast(float, u);
        }
    }
    const int r   = g >> 8;
    const int p   = g & 255;
    const int c64 = p >> 4;
    const int L   = p & 15;
    float* orow = out + (size_t)r * CO + c64 * 64 + L;
    #pragma unroll
    for (int e = 0; e < 4; ++e) orow[e * 16] = s[e];
}

extern "C" void kernel_launch(void* const* d_in, const int* in_sizes, int n_in,
                              void* d_out, int out_size, void* d_ws, size_t ws_size,
                              hipStream_t stream) {
    const float* A = (const float*)d_in[0];
    const float* W = (const float*)d_in[1];
    float* out = (float*)d_out;
    unsigned short* ws = (unsigned short*)d_ws;

    const size_t ws_needed = (size_t)SKB * SLICE_ELEMS * sizeof(unsigned short); // 16 MB

    if (ws_size >= ws_needed) {
        sconv_gemm_v7<true><<<NB * SKB, 512, 0, stream>>>(A, W, out, ws);
        reduce_splitk_v7<<<SLICE_ELEMS / 4 / 256, 256, 0, stream>>>(ws, out);
    } else {
        hipMemsetAsync(d_out, 0, (size_t)out_size * sizeof(float), stream);
        sconv_gemm_v7<false><<<NB * SKB, 512, 0, stream>>>(A, W, out, ws);
    }
}